// Round 1
// baseline (5366.027 us; speedup 1.0000x reference)
//
#include <hip/hip_runtime.h>
#include <math.h>

// Problem constants (match reference)
#define B 1024
#define N 100000
#define D 512
#define H 96
#define F 7
#define K 16
#define HF (H*F)          // 672

// Tiling for score_topk
#define QT 128            // queries per block
#define KT 64             // keys per tile
#define DK 32             // D-step staged in LDS
#define TPC 8             // tiles per chunk
#define NCHUNK (KT*TPC)   // 512 keys per block
#define NCHUNKS ((N + NCHUNK - 1) / NCHUNK)   // 196
#define QTILES (B / QT)   // 8
#define ASTR (QT + 4)     // LDS strides padded: keep 16B align, break bank conflicts
#define BSTR (KT + 4)
#define SSTR (KT + 1)
#define MCAND (NCHUNKS * K)  // 3136 candidates per query at merge

// ---------------- prep: normalize queries ----------------
__global__ void prep_q(const float* __restrict__ q, float* __restrict__ qn) {
    int w = (blockIdx.x * blockDim.x + threadIdx.x) >> 6;   // one wave per row
    int lane = threadIdx.x & 63;
    if (w >= B) return;
    const float4* row = (const float4*)(q + (size_t)w * D);
    float4 a = row[lane];
    float4 b = row[lane + 64];
    float ss = a.x*a.x + a.y*a.y + a.z*a.z + a.w*a.w
             + b.x*b.x + b.y*b.y + b.z*b.z + b.w*b.w;
#pragma unroll
    for (int off = 32; off; off >>= 1) ss += __shfl_xor(ss, off);
    float nrm = fmaxf(sqrtf(ss), 1e-12f);
    a.x /= nrm; a.y /= nrm; a.z /= nrm; a.w /= nrm;
    b.x /= nrm; b.y /= nrm; b.z /= nrm; b.w /= nrm;
    float4* o = (float4*)(qn + (size_t)w * D);
    o[lane] = a; o[lane + 64] = b;
}

// ---------------- prep: per-key scale = decay / ||k|| ----------------
__global__ void prep_k(const float* __restrict__ keys, const int* __restrict__ ts,
                       const int* __restrict__ gstep, float* __restrict__ kscale) {
    int w = (blockIdx.x * blockDim.x + threadIdx.x) >> 6;   // one wave per row
    int lane = threadIdx.x & 63;
    if (w >= N) return;
    const float4* row = (const float4*)(keys + (size_t)w * D);
    float4 a = row[lane];
    float4 b = row[lane + 64];
    float ss = a.x*a.x + a.y*a.y + a.z*a.z + a.w*a.w
             + b.x*b.x + b.y*b.y + b.z*b.z + b.w*b.w;
#pragma unroll
    for (int off = 32; off; off >>= 1) ss += __shfl_xor(ss, off);
    if (lane == 0) {
        float age = (float)(gstep[0] - ts[w]);
        float dec = powf(0.995f, age);
        kscale[w] = dec / fmaxf(sqrtf(ss), 1e-12f);
    }
}

// ---------------- fused fp32 GEMM + per-chunk top-16 ----------------
// grid: (QTILES, NCHUNKS). Same-chunk blocks adjacent in x for L2/LLC key reuse.
__global__ __launch_bounds__(256, 2)
void score_topk(const float* __restrict__ qn, const float* __restrict__ keys,
                const float* __restrict__ kscale,
                float* __restrict__ candS, int* __restrict__ candI) {
    __shared__ float As[DK * ASTR];   // 16.9 KB  (d-major, transposed)
    __shared__ float Bs[DK * BSTR];   //  8.7 KB
    __shared__ float Ss[QT * SSTR];   // 33.3 KB  sims tile for the scan

    int t = threadIdx.x;
    int qtile = blockIdx.x, chunk = blockIdx.y;
    int qbase = qtile * QT;
    int nbase = chunk * NCHUNK;
    int tq = t >> 4, tk = t & 15;     // 16x16 thread grid; 8q x 4k micro-tile

    // register-resident sorted top-16 (descending), one per thread for t<QT
    float topS[K]; int topI[K];
#pragma unroll
    for (int i = 0; i < K; ++i) { topS[i] = -INFINITY; topI[i] = 0; }

    for (int tile = 0; tile < TPC; ++tile) {
        int kbase = nbase + tile * KT;
        if (kbase >= N) break;        // uniform

        float acc[8][4];
#pragma unroll
        for (int u = 0; u < 8; ++u)
#pragma unroll
            for (int v = 0; v < 4; ++v) acc[u][v] = 0.f;

        for (int dstep = 0; dstep < D / DK; ++dstep) {
            int db = dstep * DK;
            // stage A: 128q x 32d, transposed into As[d][q]
#pragma unroll
            for (int it = 0; it < 4; ++it) {
                int l = t + it * 256;           // 0..1023
                int qq = l >> 3, dseg = l & 7;
                const float4 v = *(const float4*)(qn + (size_t)(qbase + qq) * D + db + dseg * 4);
                As[(dseg*4+0)*ASTR + qq] = v.x;
                As[(dseg*4+1)*ASTR + qq] = v.y;
                As[(dseg*4+2)*ASTR + qq] = v.z;
                As[(dseg*4+3)*ASTR + qq] = v.w;
            }
            // stage B: 64k x 32d, transposed into Bs[d][k]
#pragma unroll
            for (int it = 0; it < 2; ++it) {
                int l = t + it * 256;           // 0..511
                int kk = l >> 3, dseg = l & 7;
                int kg = kbase + kk;
                float4 v = make_float4(0.f, 0.f, 0.f, 0.f);
                if (kg < N) v = *(const float4*)(keys + (size_t)kg * D + db + dseg * 4);
                Bs[(dseg*4+0)*BSTR + kk] = v.x;
                Bs[(dseg*4+1)*BSTR + kk] = v.y;
                Bs[(dseg*4+2)*BSTR + kk] = v.z;
                Bs[(dseg*4+3)*BSTR + kk] = v.w;
            }
            __syncthreads();
#pragma unroll
            for (int dd = 0; dd < DK; ++dd) {
                float a[8], bv[4];
#pragma unroll
                for (int u = 0; u < 8; ++u) a[u] = As[dd*ASTR + tq*8 + u];
#pragma unroll
                for (int v = 0; v < 4; ++v) bv[v] = Bs[dd*BSTR + tk*4 + v];
#pragma unroll
                for (int u = 0; u < 8; ++u)
#pragma unroll
                    for (int v = 0; v < 4; ++v)
                        acc[u][v] = fmaf(a[u], bv[v], acc[u][v]);
            }
            __syncthreads();
        }

        // apply per-key scale (decay/norm); OOB keys -> -inf
#pragma unroll
        for (int v = 0; v < 4; ++v) {
            int kg = kbase + tk*4 + v;
            bool ok = kg < N;
            float sc = ok ? kscale[kg] : 0.f;
#pragma unroll
            for (int u = 0; u < 8; ++u) {
                float s = ok ? acc[u][v] * sc : -INFINITY;
                Ss[(tq*8 + u) * SSTR + tk*4 + v] = s;
            }
        }
        __syncthreads();

        // one thread per query scans its 64 sims, sorted-insert (keys in
        // increasing index order => ties keep lower index, matches lax.top_k)
        if (t < QT) {
            float mn = topS[K-1];
#pragma unroll 1
            for (int c = 0; c < KT; ++c) {
                float s = Ss[t * SSTR + c];
                if (s > mn) {
                    int id = kbase + c;
#pragma unroll
                    for (int p = 0; p < K; ++p) {
                        if (s > topS[p]) {
                            float ts0 = topS[p]; topS[p] = s; s = ts0;
                            int ti = topI[p]; topI[p] = id; id = ti;
                        }
                    }
                    mn = topS[K-1];
                }
            }
        }
        __syncthreads();
    }

    if (t < QT) {
        int gq = qbase + t;
        size_t base = ((size_t)gq * NCHUNKS + chunk) * K;
#pragma unroll
        for (int i = 0; i < K; ++i) { candS[base + i] = topS[i]; candI[base + i] = topI[i]; }
    }
}

// ---------------- merge candidates, softmax, gather, output ----------------
__global__ __launch_bounds__(256)
void merge_out(const float* __restrict__ candS, const int* __restrict__ candI,
               const float* __restrict__ values, float* __restrict__ out) {
    int b = blockIdx.x, t = threadIdx.x;
    __shared__ float sB[MCAND];
    __shared__ int   iB[MCAND];
    __shared__ float rS[4]; __shared__ int rI[4], rP[4];
    __shared__ float selS[K]; __shared__ int selI[K];
    __shared__ float wgt[K];

    size_t base = (size_t)b * MCAND;
    for (int i = t; i < MCAND; i += 256) { sB[i] = candS[base + i]; iB[i] = candI[base + i]; }
    __syncthreads();

    int lane = t & 63, wid = t >> 6;
    for (int r = 0; r < K; ++r) {
        float best = -INFINITY; int bi = 0x7fffffff, bp = -1;
        for (int i = t; i < MCAND; i += 256) {
            float v = sB[i]; int ii = iB[i];
            if (v > best || (v == best && ii < bi)) { best = v; bi = ii; bp = i; }
        }
#pragma unroll
        for (int off = 32; off; off >>= 1) {
            float ob = __shfl_xor(best, off);
            int oi = __shfl_xor(bi, off);
            int op = __shfl_xor(bp, off);
            if (ob > best || (ob == best && oi < bi)) { best = ob; bi = oi; bp = op; }
        }
        if (lane == 0) { rS[wid] = best; rI[wid] = bi; rP[wid] = bp; }
        __syncthreads();
        if (t == 0) {
            float bb = rS[0]; int bbi = rI[0], bbp = rP[0];
            for (int w = 1; w < 4; ++w)
                if (rS[w] > bb || (rS[w] == bb && rI[w] < bbi)) { bb = rS[w]; bbi = rI[w]; bbp = rP[w]; }
            selS[r] = bb; selI[r] = bbi;
            if (bbp >= 0) sB[bbp] = -INFINITY;
        }
        __syncthreads();
    }

    if (t == 0) {
        // replicate reference exactly: y = s/T; softmax(y); mask s>=0; renorm by (sum+eps)
        float y[K], e[K];
        for (int k = 0; k < K; ++k) y[k] = selS[k] / 0.1f;
        float ymax = y[0];                       // selS is sorted descending
        float Z = 0.f;
        for (int k = 0; k < K; ++k) { e[k] = expf(y[k] - ymax); Z += e[k]; }
        float Z2 = 0.f;
        for (int k = 0; k < K; ++k) {
            float w = e[k] / Z;
            if (!(selS[k] >= 0.0f)) w = 0.f;
            e[k] = w; Z2 += w;
        }
        for (int k = 0; k < K; ++k) wgt[k] = e[k] / (Z2 + 1e-8f);
    }
    __syncthreads();

    for (int e0 = t; e0 < HF; e0 += 256) {
        float o = 0.f;
#pragma unroll
        for (int k = 0; k < K; ++k) {
            int idx = selI[k];
            idx = (idx >= 0 && idx < N) ? idx : 0;   // defensive; weight is 0 if invalid
            o += wgt[k] * values[(size_t)idx * HF + e0];
        }
        out[(size_t)b * HF + e0] = o;
    }
}

extern "C" void kernel_launch(void* const* d_in, const int* in_sizes, int n_in,
                              void* d_out, int out_size, void* d_ws, size_t ws_size,
                              hipStream_t stream) {
    const float* query  = (const float*)d_in[0];
    const float* keys   = (const float*)d_in[1];
    const float* values = (const float*)d_in[2];
    const int*   ts     = (const int*)d_in[3];   // int inputs arrive as int32
    const int*   gstep  = (const int*)d_in[4];
    float* out = (float*)d_out;

    // workspace layout (elements): qn[B*D] | kscale[N] | candS[B*NCHUNKS*K] | candI[...]
    float* qn     = (float*)d_ws;
    float* kscale = qn + (size_t)B * D;
    float* candS  = kscale + N;
    int*   candI  = (int*)(candS + (size_t)B * NCHUNKS * K);

    prep_q<<<B / 4, 256, 0, stream>>>(query, qn);
    prep_k<<<(N + 3) / 4, 256, 0, stream>>>(keys, ts, gstep, kscale);
    dim3 g2(QTILES, NCHUNKS);
    score_topk<<<g2, 256, 0, stream>>>(qn, keys, kscale, candS, candI);
    merge_out<<<B, 256, 0, stream>>>(candS, candI, values, out);
}

// Round 2
// 2078.164 us; speedup vs baseline: 2.5821x; 2.5821x over previous
//
#include <hip/hip_runtime.h>
#include <math.h>

// Problem constants
#define B 1024
#define N 100000
#define D 512
#define H 96
#define F 7
#define K 16
#define HF (H*F)            // 672

// Scoring tiles
#define QT 128              // queries per block
#define KTILE 64            // keys per MFMA macro-tile
#define TPC 16              // k-tiles per chunk
#define NCHUNK (KTILE*TPC)  // 1024 keys per block
#define NCHUNKS 98          // ceil(N/NCHUNK)
#define NPAD (NCHUNKS*NCHUNK) // 100352 (kb padded with zero rows)
#define SSTR (KTILE+1)      // Ss row stride (odd -> bank spread)
#define CPQ (NCHUNKS*32)    // 3136 candidates per query (2 half-lists x16 per chunk)
#define CSEL 32             // coarse candidates rescored in fp32

typedef __attribute__((ext_vector_type(8))) short shortx8;   // 8 bf16 (4 VGPRs)
typedef __attribute__((ext_vector_type(4))) float floatx4;   // MFMA accumulator

__device__ __forceinline__ unsigned short f2bf(float f) {    // RTN-even fp32->bf16
    unsigned int u = __float_as_uint(f);
    u += 0x7FFF + ((u >> 16) & 1);
    return (unsigned short)(u >> 16);
}

// async 16B/lane global->LDS; LDS dest is wave-uniform base + lane*16
#define ASYNC16(g, l) __builtin_amdgcn_global_load_lds( \
    (__attribute__((address_space(1))) void*)(g), \
    (__attribute__((address_space(3))) void*)(l), 16, 0, 0)

// ---------------- prep: normalize queries (fp32 + bf16 copies) ----------------
__global__ void prep_q(const float* __restrict__ q, float* __restrict__ qn,
                       unsigned short* __restrict__ qb) {
    int w = (blockIdx.x * blockDim.x + threadIdx.x) >> 6;   // one wave per row
    int l = threadIdx.x & 63;
    if (w >= B) return;
    const float4* row = (const float4*)(q + (size_t)w * D);
    float4 a = row[l], b = row[l + 64];
    float ss = a.x*a.x + a.y*a.y + a.z*a.z + a.w*a.w
             + b.x*b.x + b.y*b.y + b.z*b.z + b.w*b.w;
#pragma unroll
    for (int off = 32; off; off >>= 1) ss += __shfl_xor(ss, off);
    float nrm = fmaxf(sqrtf(ss), 1e-12f);
    a.x /= nrm; a.y /= nrm; a.z /= nrm; a.w /= nrm;
    b.x /= nrm; b.y /= nrm; b.z /= nrm; b.w /= nrm;
    float4* o = (float4*)(qn + (size_t)w * D);
    o[l] = a; o[l + 64] = b;
    unsigned short* ob = qb + (size_t)w * D;
    *(ushort4*)(ob + 4*l)       = make_ushort4(f2bf(a.x), f2bf(a.y), f2bf(a.z), f2bf(a.w));
    *(ushort4*)(ob + 256 + 4*l) = make_ushort4(f2bf(b.x), f2bf(b.y), f2bf(b.z), f2bf(b.w));
}

// ---------------- prep: kscale fp32 + pre-scaled bf16 keys (zero-padded) ------
__global__ void prep_k(const float* __restrict__ keys, const int* __restrict__ ts,
                       const int* __restrict__ gstep, float* __restrict__ kscale,
                       unsigned short* __restrict__ kb) {
    int w = (blockIdx.x * blockDim.x + threadIdx.x) >> 6;   // one wave per row
    int l = threadIdx.x & 63;
    if (w >= NPAD) return;
    unsigned short* dst = kb + (size_t)w * D;
    if (w >= N) {                                           // zero pad rows
        *(ushort4*)(dst + 4*l)       = make_ushort4(0,0,0,0);
        *(ushort4*)(dst + 256 + 4*l) = make_ushort4(0,0,0,0);
        return;
    }
    const float4* row = (const float4*)(keys + (size_t)w * D);
    float4 a = row[l], b = row[l + 64];
    float ss = a.x*a.x + a.y*a.y + a.z*a.z + a.w*a.w
             + b.x*b.x + b.y*b.y + b.z*b.z + b.w*b.w;
#pragma unroll
    for (int off = 32; off; off >>= 1) ss += __shfl_xor(ss, off);
    float age = (float)(gstep[0] - ts[w]);
    float sc = powf(0.995f, age) / fmaxf(sqrtf(ss), 1e-12f);
    if (l == 0) kscale[w] = sc;
    *(ushort4*)(dst + 4*l)       = make_ushort4(f2bf(a.x*sc), f2bf(a.y*sc), f2bf(a.z*sc), f2bf(a.w*sc));
    *(ushort4*)(dst + 256 + 4*l) = make_ushort4(f2bf(b.x*sc), f2bf(b.y*sc), f2bf(b.z*sc), f2bf(b.w*sc));
}

// ---------------- bf16 MFMA coarse scoring + fused per-chunk top-16 ----------
// grid (8 qtiles, 98 chunks), 256 threads = 4 waves (2q x 2k wave grid)
__global__ __launch_bounds__(256, 3)
void score_topk(const unsigned short* __restrict__ qb,
                const unsigned short* __restrict__ kb,
                float* __restrict__ candS, int* __restrict__ candI) {
    __shared__ __align__(16) unsigned short As[QT * 32];     // 8 KB  (q-major, 32 d)
    __shared__ __align__(16) unsigned short Bs[KTILE * 32];  // 4 KB
    __shared__ float Ss[QT * SSTR];                          // 33.3 KB

    const int t = threadIdx.x;
    const int w = t >> 6, l = t & 63;
    const int qbase = blockIdx.x * QT;
    const int nbase = blockIdx.y * NCHUNK;
    const int m = l & 15, quad = l >> 4;
    const int wq = w & 1, wk = w >> 1;

    // staging lanes: 16 rows x 64B per instruction
    const int srow = l >> 2;            // 0..15
    const int scol = (l & 3) * 8;       // bf16 col
    const unsigned short* gA0 = qb + (size_t)(qbase + w*32 + srow) * D + scol;
    const unsigned short* gA1 = gA0 + (size_t)16 * D;
    unsigned short* lA0 = As + (w*32) * 32;      // wave-uniform LDS bases
    unsigned short* lA1 = As + (w*32 + 16) * 32;
    unsigned short* lB  = Bs + (w*16) * 32;

    // fragment read bases (A-operand layout: row=lane&15, k=quad*8+j)
    const unsigned short* aBase = As + (size_t)(wq*64 + m) * 32 + quad*8;
    const unsigned short* bBase = Bs + (size_t)(wk*32 + m) * 32 + quad*8;

    float topS[K]; int topI[K];
#pragma unroll
    for (int i = 0; i < K; ++i) { topS[i] = -INFINITY; topI[i] = 0; }
    const int q = t & 127, ch = t >> 7;          // scan: query + column half

    for (int kt = 0; kt < TPC; ++kt) {
        const unsigned short* gB = kb + (size_t)(nbase + kt*KTILE + w*16 + srow) * D + scol;
        floatx4 acc[4][2];
#pragma unroll
        for (int i = 0; i < 4; ++i)
#pragma unroll
            for (int j = 0; j < 2; ++j) acc[i][j] = (floatx4){0.f, 0.f, 0.f, 0.f};

        for (int ds = 0; ds < D/32; ++ds) {
            ASYNC16(gA0 + ds*32, lA0);
            ASYNC16(gA1 + ds*32, lA1);
            ASYNC16(gB  + ds*32, lB);
            __syncthreads();                      // drains vmcnt before barrier
            shortx8 af[4], bf[2];
#pragma unroll
            for (int qt = 0; qt < 4; ++qt) af[qt] = *(const shortx8*)(aBase + qt*512);
#pragma unroll
            for (int kk = 0; kk < 2; ++kk) bf[kk] = *(const shortx8*)(bBase + kk*512);
#pragma unroll
            for (int qt = 0; qt < 4; ++qt)
#pragma unroll
                for (int kk = 0; kk < 2; ++kk)
                    acc[qt][kk] = __builtin_amdgcn_mfma_f32_16x16x32_bf16(
                        af[qt], bf[kk], acc[qt][kk], 0, 0, 0);
            __syncthreads();
        }

        // C layout: col(key)=lane&15, row(query)=quad*4+reg
#pragma unroll
        for (int qt = 0; qt < 4; ++qt)
#pragma unroll
            for (int kk = 0; kk < 2; ++kk)
#pragma unroll
                for (int r = 0; r < 4; ++r) {
                    int ql = wq*64 + qt*16 + quad*4 + r;
                    int kl = wk*32 + kk*16 + m;
                    Ss[ql*SSTR + kl] = acc[qt][kk][r];
                }
        __syncthreads();

        // all 256 threads scan: query q, 32-column half ch
        {
            int kgbase = nbase + kt*KTILE + ch*32;
            float mn = topS[K-1];
#pragma unroll 1
            for (int c = 0; c < 32; ++c) {
                int gidx = kgbase + c;
                if (gidx >= N) break;
                float s = Ss[q*SSTR + ch*32 + c];
                if (s > mn) {
                    int id = gidx;
#pragma unroll
                    for (int p = 0; p < K; ++p) {
                        if (s > topS[p]) {
                            float t0 = topS[p]; topS[p] = s; s = t0;
                            int t1 = topI[p]; topI[p] = id; id = t1;
                        }
                    }
                    mn = topS[K-1];
                }
            }
        }
        // no barrier needed: next Ss write is 32 barriers away
    }

    size_t cb = ((size_t)(qbase + q) * NCHUNKS + blockIdx.y) * 32 + ch*16;
#pragma unroll
    for (int i = 0; i < K; ++i) { candS[cb + i] = topS[i]; candI[cb + i] = topI[i]; }
}

// ------- merge 3136 coarse cands -> top-32 -> fp32 rescore -> top-16 -> out ---
__global__ __launch_bounds__(256)
void merge_rescore(const float* __restrict__ candS, const int* __restrict__ candI,
                   const float* __restrict__ qn, const float* __restrict__ keys,
                   const float* __restrict__ kscale, const float* __restrict__ values,
                   float* __restrict__ out) {
    int b = blockIdx.x, t = threadIdx.x;
    __shared__ float sB[CPQ];
    __shared__ int   iB[CPQ];
    __shared__ float qrow[D];
    __shared__ float rS[4]; __shared__ int rI[4], rP[4];
    __shared__ int   cIdx[CSEL];
    __shared__ float eS[CSEL];
    __shared__ float wgt[K]; __shared__ int wIdx[K];

    size_t base = (size_t)b * CPQ;
    for (int i = t; i < CPQ; i += 256) { sB[i] = candS[base + i]; iB[i] = candI[base + i]; }
    for (int i = t; i < D; i += 256) qrow[i] = qn[(size_t)b * D + i];
    __syncthreads();

    int lane = t & 63, w = t >> 6;
    for (int r = 0; r < CSEL; ++r) {            // coarse top-32 (score desc, idx asc)
        float best = -INFINITY; int bi = 0x7fffffff, bp = -1;
        for (int i = t; i < CPQ; i += 256) {
            float v = sB[i]; int ii = iB[i];
            if (v > best || (v == best && ii < bi)) { best = v; bi = ii; bp = i; }
        }
#pragma unroll
        for (int off = 32; off; off >>= 1) {
            float ob = __shfl_xor(best, off);
            int oi = __shfl_xor(bi, off);
            int op = __shfl_xor(bp, off);
            if (ob > best || (ob == best && oi < bi)) { best = ob; bi = oi; bp = op; }
        }
        if (lane == 0) { rS[w] = best; rI[w] = bi; rP[w] = bp; }
        __syncthreads();
        if (t == 0) {
            float bb = rS[0]; int bbi = rI[0], bbp = rP[0];
            for (int j = 1; j < 4; ++j)
                if (rS[j] > bb || (rS[j] == bb && rI[j] < bbi)) { bb = rS[j]; bbi = rI[j]; bbp = rP[j]; }
            cIdx[r] = bbi;
            if (bbp >= 0) sB[bbp] = -INFINITY;
        }
        __syncthreads();
    }

    // exact fp32 rescore: wave w handles candidates w, w+4, ...
    for (int c = w; c < CSEL; c += 4) {
        int idx = cIdx[c];
        const float4* kr = (const float4*)(keys + (size_t)idx * D);
        const float4* qr = (const float4*)qrow;
        float4 k1 = kr[lane], k2 = kr[lane + 64];
        float4 q1 = qr[lane], q2 = qr[lane + 64];
        float p = q1.x*k1.x + q1.y*k1.y + q1.z*k1.z + q1.w*k1.w
                + q2.x*k2.x + q2.y*k2.y + q2.z*k2.z + q2.w*k2.w;
#pragma unroll
        for (int off = 32; off; off >>= 1) p += __shfl_xor(p, off);
        if (lane == 0) eS[c] = p * kscale[idx];
    }
    __syncthreads();

    if (t == 0) {                                // exact top-16 + softmax weights
        float s[CSEL]; int id[CSEL];
        for (int i = 0; i < CSEL; ++i) { s[i] = eS[i]; id[i] = cIdx[i]; }
        float selS[K]; int selI[K];
        for (int r = 0; r < K; ++r) {
            float bb = -INFINITY; int bbi = 0x7fffffff, bbp = -1;
            for (int i = 0; i < CSEL; ++i)
                if (s[i] > bb || (s[i] == bb && id[i] < bbi)) { bb = s[i]; bbi = id[i]; bbp = i; }
            selS[r] = bb; selI[r] = bbi; s[bbp] = -INFINITY;
        }
        float y[K], e[K];
        for (int k = 0; k < K; ++k) y[k] = selS[k] / 0.1f;
        float ymax = y[0];                       // sorted desc
        float Z = 0.f;
        for (int k = 0; k < K; ++k) { e[k] = expf(y[k] - ymax); Z += e[k]; }
        float Z2 = 0.f;
        for (int k = 0; k < K; ++k) {
            float ww = e[k] / Z;
            if (!(selS[k] >= 0.0f)) ww = 0.f;
            e[k] = ww; Z2 += ww;
        }
        for (int k = 0; k < K; ++k) { wgt[k] = e[k] / (Z2 + 1e-8f); wIdx[k] = selI[k]; }
    }
    __syncthreads();

    for (int e0 = t; e0 < HF; e0 += 256) {
        float o = 0.f;
#pragma unroll
        for (int k = 0; k < K; ++k)
            o += wgt[k] * values[(size_t)wIdx[k] * HF + e0];
        out[(size_t)b * HF + e0] = o;
    }
}

extern "C" void kernel_launch(void* const* d_in, const int* in_sizes, int n_in,
                              void* d_out, int out_size, void* d_ws, size_t ws_size,
                              hipStream_t stream) {
    const float* query  = (const float*)d_in[0];
    const float* keys   = (const float*)d_in[1];
    const float* values = (const float*)d_in[2];
    const int*   ts     = (const int*)d_in[3];
    const int*   gstep  = (const int*)d_in[4];
    float* out = (float*)d_out;

    // workspace carve-out (256B aligned)
    char* p = (char*)d_ws;
    size_t o = 0;
    auto alloc = [&](size_t bytes) { char* r = p + o; o = (o + bytes + 255) & ~(size_t)255; return r; };
    float*          qn     = (float*)alloc((size_t)B * D * 4);
    unsigned short* qb     = (unsigned short*)alloc((size_t)B * D * 2);
    float*          kscale = (float*)alloc((size_t)N * 4);
    unsigned short* kb     = (unsigned short*)alloc((size_t)NPAD * D * 2);
    float*          candS  = (float*)alloc((size_t)B * CPQ * 4);
    int*            candI  = (int*)alloc((size_t)B * CPQ * 4);

    prep_q<<<B / 4, 256, 0, stream>>>(query, qn, qb);
    prep_k<<<NPAD / 4, 256, 0, stream>>>(keys, ts, gstep, kscale, kb);
    dim3 g2(B / QT, NCHUNKS);
    score_topk<<<g2, 256, 0, stream>>>(qb, kb, candS, candI);
    merge_rescore<<<B, 256, 0, stream>>>(candS, candI, qn, keys, kscale, values, out);
}